// Round 1
// baseline (10495.182 us; speedup 1.0000x reference)
//
#include <hip/hip_runtime.h>
#include <hip/hip_bf16.h>

// LSTM T=512 B=64 D=H=512. fp32 in/out, bf16 MFMA compute (harness uses bf16 floor threshold).
//
// Strategy: one persistent kernel, 64 WGs x 256 thr (1 WG/CU, 1 wave/SIMD -> big VGPR budget).
// Custom global counter barrier, double-buffered H (bf16) in ws, C-state in registers.
// Weights pre-packed to MFMA B-frag layout, held in VGPRs for the whole scan.
// x-projection of step t+1 computed after signaling step t (hides off critical path).

#define NT 512
#define NB 64
#define ND 512
#define NH 512
#define NWG 64

typedef short bf16x8 __attribute__((ext_vector_type(8)));
typedef float f32x4 __attribute__((ext_vector_type(4)));

// ws layout (bytes)
#define WXP_OFF   0u
#define WHP_OFF   (2u*1024u*1024u)
#define BCAT_OFF  (4u*1024u*1024u)
#define HBUF_OFF  (BCAT_OFF + 8192u)      // 2 x [64][512] bf16 = 131072 B
#define CNT_OFF   (HBUF_OFF + 131072u)
#define WS_NEED   (CNT_OFF + 128u)

static __device__ __forceinline__ unsigned short f2bf(float f) {
  __hip_bfloat16 h = __float2bfloat16(f);
  return __builtin_bit_cast(unsigned short, h);
}

static __device__ __forceinline__ float sigm(float x) {
  float e = __expf(-x);
  return __fdividef(1.0f, 1.0f + e);
}
static __device__ __forceinline__ float tanhfast(float x) {
  float e = __expf(2.0f * x);
  return 1.0f - __fdividef(2.0f, e + 1.0f);
}

// Pack W_x / W_h (fp32 [K][H] row-major) into bf16 MFMA B-fragment order:
// chunk idx = (ct*16 + ks)*64 + lane ; chunk = B[k0..k0+8)[col], k0 = ks*32+(lane>>4)*8,
// col = ct*16 + (lane&15) in PACKED column space: p = wg*32 + gate*8 + h%8, wg = h/8.
__global__ __launch_bounds__(256) void pack_weights(
    const float* __restrict__ Wx0, const float* __restrict__ Wh0, const float* __restrict__ b0,
    const float* __restrict__ Wx1, const float* __restrict__ Wh1, const float* __restrict__ b1,
    const float* __restrict__ Wx2, const float* __restrict__ Wh2, const float* __restrict__ b2,
    const float* __restrict__ Wx3, const float* __restrict__ Wh3, const float* __restrict__ b3,
    uint4* __restrict__ Wxp, uint4* __restrict__ Whp, float* __restrict__ bcat)
{
  int gid = blockIdx.x * 256 + threadIdx.x;   // 0 .. 262143
  int s   = gid >> 17;                        // 0 = Wx, 1 = Wh
  int idx = gid & 131071;
  int l   = idx & 63;
  int ks  = (idx >> 6) & 15;
  int ct  = idx >> 10;                        // 0..127
  int p   = ct * 16 + (l & 15);               // packed col
  int k0  = ks * 32 + (l >> 4) * 8;
  int wg = p >> 5, r = p & 31, gate = r >> 3;
  int h  = wg * 8 + (r & 7);
  const float* W;
  if (s == 0) W = (gate==0) ? Wx0 : (gate==1) ? Wx1 : (gate==2) ? Wx2 : Wx3;
  else        W = (gate==0) ? Wh0 : (gate==1) ? Wh1 : (gate==2) ? Wh2 : Wh3;
  unsigned int wds[4];
  #pragma unroll
  for (int q = 0; q < 4; ++q) {
    unsigned short lo = f2bf(W[(size_t)(k0 + 2*q    ) * NH + h]);
    unsigned short hi = f2bf(W[(size_t)(k0 + 2*q + 1) * NH + h]);
    wds[q] = (unsigned int)lo | ((unsigned int)hi << 16);
  }
  uint4 out; out.x = wds[0]; out.y = wds[1]; out.z = wds[2]; out.w = wds[3];
  if (s == 0) Wxp[idx] = out; else Whp[idx] = out;
  if (gid < 2048) {  // bias pack: bcat[p] = b_gate[h]
    int pp = gid; int wg2 = pp >> 5, r2 = pp & 31, g2 = r2 >> 3;
    int h2 = wg2 * 8 + (r2 & 7);
    const float* bb = (g2==0) ? b0 : (g2==1) ? b1 : (g2==2) ? b2 : b3;
    bcat[pp] = bb[h2];
  }
}

__global__ __launch_bounds__(256, 1) void lstm_scan(
    const float* __restrict__ x,          // [T*B, D] fp32
    const uint4* __restrict__ Wxp,
    const uint4* __restrict__ Whp,
    const float* __restrict__ bcat,
    unsigned short* __restrict__ hb,      // [2][64][512] bf16
    unsigned int* __restrict__ cnt,
    float* __restrict__ out)              // outs [T,B,H] | Hf [B,H] | Cf [B,H]
{
  const int wg = blockIdx.x;
  const int tid = threadIdx.x;
  const int w = tid >> 6;              // wave 0..3 -> row tile
  const int lane = tid & 63;
  const int l15 = lane & 15, l4 = lane >> 4, l7 = lane & 7;
  const bool hiHalf = (lane & 8) != 0;

  // ---- load weight fragments into registers (persist across all 512 steps) ----
  bf16x8 bx0[16], bx1[16], bh0[16], bh1[16];
  {
    const int cg0 = wg * 2, cg1 = wg * 2 + 1;
    #pragma unroll
    for (int ks = 0; ks < 16; ++ks) {
      bx0[ks] = __builtin_bit_cast(bf16x8, Wxp[(cg0 * 16 + ks) * 64 + lane]);
      bx1[ks] = __builtin_bit_cast(bf16x8, Wxp[(cg1 * 16 + ks) * 64 + lane]);
      bh0[ks] = __builtin_bit_cast(bf16x8, Whp[(cg0 * 16 + ks) * 64 + lane]);
      bh1[ks] = __builtin_bit_cast(bf16x8, Whp[(cg1 * 16 + ks) * 64 + lane]);
    }
  }
  const float bias0 = bcat[wg * 32 + l15];
  const float bias1 = bcat[wg * 32 + 16 + l15];

  const int arow = w * 16 + l15;       // A-operand row (batch index b)
  const int hcol = wg * 8 + l7;        // owned h column
  float c_state[2] = {0.f, 0.f};

  f32x4 acc0, acc1;

  // x-part of step tt: acc = bias + x_tt @ Wx   (bf16 by truncation: cheap, well within tol)
  auto xpart = [&](int tt) {
    acc0 = f32x4{bias0, bias0, bias0, bias0};
    acc1 = f32x4{bias1, bias1, bias1, bias1};
    const float* xs = x + ((size_t)tt * NB + arow) * ND + l4 * 8;
    #pragma unroll
    for (int ks = 0; ks < 16; ++ks) {
      float4 f0 = *(const float4*)(xs + ks * 32);
      float4 f1 = *(const float4*)(xs + ks * 32 + 4);
      unsigned int u0 = __builtin_amdgcn_perm(__builtin_bit_cast(unsigned int, f0.y),
                                              __builtin_bit_cast(unsigned int, f0.x), 0x07060302u);
      unsigned int u1 = __builtin_amdgcn_perm(__builtin_bit_cast(unsigned int, f0.w),
                                              __builtin_bit_cast(unsigned int, f0.z), 0x07060302u);
      unsigned int u2 = __builtin_amdgcn_perm(__builtin_bit_cast(unsigned int, f1.y),
                                              __builtin_bit_cast(unsigned int, f1.x), 0x07060302u);
      unsigned int u3 = __builtin_amdgcn_perm(__builtin_bit_cast(unsigned int, f1.w),
                                              __builtin_bit_cast(unsigned int, f1.z), 0x07060302u);
      uint4 uu; uu.x = u0; uu.y = u1; uu.z = u2; uu.w = u3;
      bf16x8 a = __builtin_bit_cast(bf16x8, uu);
      acc0 = __builtin_amdgcn_mfma_f32_16x16x32_bf16(a, bx0[ks], acc0, 0, 0, 0);
      acc1 = __builtin_amdgcn_mfma_f32_16x16x32_bf16(a, bx1[ks], acc1, 0, 0, 0);
    }
  };

  xpart(0);

  #pragma unroll 1
  for (int t = 0; t < NT; ++t) {
    // ---- wait for all WGs to finish step t-1 ----
    if (t > 0) {
      if (tid == 0) {
        unsigned target = (unsigned)(NWG * t);
        while (__hip_atomic_load(cnt, __ATOMIC_ACQUIRE, __HIP_MEMORY_SCOPE_AGENT) < target) { }
      }
      __syncthreads();
    }

    // ---- h-part: acc += H_{t-1} @ Wh  (A from global bf16 Hbuf, B from registers) ----
    {
      const unsigned short* hsrc = hb + ((t + 1) & 1) * (NB * NH) + arow * NH + l4 * 8;
      uint4 ahw[16];
      #pragma unroll
      for (int ks = 0; ks < 16; ++ks) ahw[ks] = *(const uint4*)(hsrc + ks * 32);
      #pragma unroll
      for (int ks = 0; ks < 16; ++ks) {
        bf16x8 a = __builtin_bit_cast(bf16x8, ahw[ks]);
        acc0 = __builtin_amdgcn_mfma_f32_16x16x32_bf16(a, bh0[ks], acc0, 0, 0, 0);
        acc1 = __builtin_amdgcn_mfma_f32_16x16x32_bf16(a, bh1[ks], acc1, 0, 0, 0);
      }
    }

    // ---- gate epilogue: each lane handles 2 of the 4 acc rows (j split by lane&8) ----
    float hv[2];
    int brow[2];
    #pragma unroll
    for (int jj = 0; jj < 2; ++jj) {
      float a0own = hiHalf ? acc0[2 + jj] : acc0[jj];
      float a0opp = hiHalf ? acc0[jj]     : acc0[2 + jj];
      float a1own = hiHalf ? acc1[2 + jj] : acc1[jj];
      float a1opp = hiHalf ? acc1[jj]     : acc1[2 + jj];
      float a0x = __shfl_xor(a0opp, 8);
      float a1x = __shfl_xor(a1opp, 8);
      float pi = hiHalf ? a0x   : a0own;   // gate i  (packed cols 0..7)
      float pf = hiHalf ? a0own : a0x;     // gate f  (cols 8..15)
      float po = hiHalf ? a1x   : a1own;   // gate o  (cols 16..23)
      float pc = hiHalf ? a1own : a1x;     // gate c~ (cols 24..31)
      float I = sigm(pi), F = sigm(pf), O = sigm(po), Cc = tanhfast(pc);
      float c = F * c_state[jj] + I * Cc;
      c_state[jj] = c;
      hv[jj] = O * tanhfast(c);
      int j = (hiHalf ? 2 : 0) + jj;
      brow[jj] = w * 16 + l4 * 4 + j;
      hb[(t & 1) * (NB * NH) + brow[jj] * NH + hcol] = f2bf(hv[jj]);
    }

    // ---- publish H_t, signal ----
    __threadfence();
    __syncthreads();
    if (tid == 0)
      __hip_atomic_fetch_add(cnt, 1u, __ATOMIC_RELEASE, __HIP_MEMORY_SCOPE_AGENT);

    // ---- off critical path: fp32 outputs + next step's x projection ----
    #pragma unroll
    for (int jj = 0; jj < 2; ++jj)
      out[((size_t)t * NB + brow[jj]) * NH + hcol] = hv[jj];
    if (t == NT - 1) {
      #pragma unroll
      for (int jj = 0; jj < 2; ++jj) {
        out[(size_t)NT * NB * NH + brow[jj] * NH + hcol] = hv[jj];           // Hf
        out[(size_t)NT * NB * NH + NB * NH + brow[jj] * NH + hcol] = c_state[jj]; // Cf
      }
    } else {
      xpart(t + 1);
    }
  }
}

extern "C" void kernel_launch(void* const* d_in, const int* in_sizes, int n_in,
                              void* d_out, int out_size, void* d_ws, size_t ws_size,
                              hipStream_t stream) {
  const float* x = (const float*)d_in[0];
  // gate order i,f,o,c : Wx = d_in[1,4,7,10], Wh = d_in[2,5,8,11], b = d_in[3,6,9,12]
  const float* Wx0 = (const float*)d_in[1];
  const float* Wh0 = (const float*)d_in[2];
  const float* b0  = (const float*)d_in[3];
  const float* Wx1 = (const float*)d_in[4];
  const float* Wh1 = (const float*)d_in[5];
  const float* b1  = (const float*)d_in[6];
  const float* Wx2 = (const float*)d_in[7];
  const float* Wh2 = (const float*)d_in[8];
  const float* b2  = (const float*)d_in[9];
  const float* Wx3 = (const float*)d_in[10];
  const float* Wh3 = (const float*)d_in[11];
  const float* b3  = (const float*)d_in[12];

  char* ws = (char*)d_ws;
  if (ws_size < (size_t)WS_NEED) return;  // ~4.33 MB needed
  uint4* Wxp = (uint4*)(ws + WXP_OFF);
  uint4* Whp = (uint4*)(ws + WHP_OFF);
  float* bcat = (float*)(ws + BCAT_OFF);
  unsigned short* hbuf = (unsigned short*)(ws + HBUF_OFF);
  unsigned int* cnt = (unsigned int*)(ws + CNT_OFF);

  // zero H double-buffer (t=0 reads buffer 1) + barrier counter
  hipMemsetAsync(ws + HBUF_OFF, 0, 131072u + 128u, stream);

  pack_weights<<<1024, 256, 0, stream>>>(Wx0, Wh0, b0, Wx1, Wh1, b1,
                                         Wx2, Wh2, b2, Wx3, Wh3, b3,
                                         Wxp, Whp, bcat);

  lstm_scan<<<NWG, 256, 0, stream>>>(x, Wxp, Whp, bcat, hbuf, cnt, (float*)d_out);
}

// Round 2
// 5603.156 us; speedup vs baseline: 1.8731x; 1.8731x over previous
//
#include <hip/hip_runtime.h>
#include <hip/hip_bf16.h>

// LSTM T=512 B=64 D=H=512. fp32 in/out, bf16 MFMA compute.
//
// R1: fence-free cross-XCD sync. H published via relaxed agent-scope (sc1) dword
// stores, read via sc0+sc1 dwordx4 loads (bypass stale per-XCD L2). Barrier =
// per-WG epoch flags (relaxed sc1 store + 64-lane parallel relaxed sc1 poll).
// No __threadfence, no atomic RMW, no acquire-invalidate in the loop.

#define NT 512
#define NB 64
#define ND 512
#define NH 512
#define NWG 64

typedef short bf16x8 __attribute__((ext_vector_type(8)));
typedef float f32x4 __attribute__((ext_vector_type(4)));

// ws layout (bytes)
#define WXP_OFF   0u
#define WHP_OFF   (2u*1024u*1024u)
#define BCAT_OFF  (4u*1024u*1024u)
#define HBUF_OFF  (BCAT_OFF + 8192u)      // 2 x [64][512] bf16 = 131072 B
#define FLAG_OFF  (HBUF_OFF + 131072u)    // 64 x u32 epoch flags
#define WS_NEED   (FLAG_OFF + 256u)

static __device__ __forceinline__ unsigned short f2bf(float f) {
  __hip_bfloat16 h = __float2bfloat16(f);
  return __builtin_bit_cast(unsigned short, h);
}

static __device__ __forceinline__ float sigm(float x) {
  float e = __expf(-x);
  return __fdividef(1.0f, 1.0f + e);
}
static __device__ __forceinline__ float tanhfast(float x) {
  float e = __expf(2.0f * x);
  return 1.0f - __fdividef(2.0f, e + 1.0f);
}

// Pack W_x / W_h (fp32 [K][H] row-major) into bf16 MFMA B-fragment order.
// Packed column space: p = wg*32 + gate*8 + (h%8), wg = h/8.
__global__ __launch_bounds__(256) void pack_weights(
    const float* __restrict__ Wx0, const float* __restrict__ Wh0, const float* __restrict__ b0,
    const float* __restrict__ Wx1, const float* __restrict__ Wh1, const float* __restrict__ b1,
    const float* __restrict__ Wx2, const float* __restrict__ Wh2, const float* __restrict__ b2,
    const float* __restrict__ Wx3, const float* __restrict__ Wh3, const float* __restrict__ b3,
    uint4* __restrict__ Wxp, uint4* __restrict__ Whp, float* __restrict__ bcat)
{
  int gid = blockIdx.x * 256 + threadIdx.x;   // 0 .. 262143
  int s   = gid >> 17;                        // 0 = Wx, 1 = Wh
  int idx = gid & 131071;
  int l   = idx & 63;
  int ks  = (idx >> 6) & 15;
  int ct  = idx >> 10;                        // 0..127
  int p   = ct * 16 + (l & 15);               // packed col
  int k0  = ks * 32 + (l >> 4) * 8;
  int wg = p >> 5, r = p & 31, gate = r >> 3;
  int h  = wg * 8 + (r & 7);
  const float* W;
  if (s == 0) W = (gate==0) ? Wx0 : (gate==1) ? Wx1 : (gate==2) ? Wx2 : Wx3;
  else        W = (gate==0) ? Wh0 : (gate==1) ? Wh1 : (gate==2) ? Wh2 : Wh3;
  unsigned int wds[4];
  #pragma unroll
  for (int q = 0; q < 4; ++q) {
    unsigned short lo = f2bf(W[(size_t)(k0 + 2*q    ) * NH + h]);
    unsigned short hi = f2bf(W[(size_t)(k0 + 2*q + 1) * NH + h]);
    wds[q] = (unsigned int)lo | ((unsigned int)hi << 16);
  }
  uint4 out; out.x = wds[0]; out.y = wds[1]; out.z = wds[2]; out.w = wds[3];
  if (s == 0) Wxp[idx] = out; else Whp[idx] = out;
  if (gid < 2048) {  // bias pack: bcat[p] = b_gate[h]
    int pp = gid; int wg2 = pp >> 5, r2 = pp & 31, g2 = r2 >> 3;
    int h2 = wg2 * 8 + (r2 & 7);
    const float* bb = (g2==0) ? b0 : (g2==1) ? b1 : (g2==2) ? b2 : b3;
    bcat[pp] = bb[h2];
  }
}

__global__ __launch_bounds__(256, 1) void lstm_scan(
    const float* __restrict__ x,          // [T*B, D] fp32
    const uint4* __restrict__ Wxp,
    const uint4* __restrict__ Whp,
    const float* __restrict__ bcat,
    unsigned short* __restrict__ hb,      // [2][64][512] bf16
    unsigned int* __restrict__ flags,     // [64] epoch flags
    float* __restrict__ out)              // outs [T,B,H] | Hf [B,H] | Cf [B,H]
{
  const int wg = blockIdx.x;
  const int tid = threadIdx.x;
  const int w = tid >> 6;              // wave 0..3 -> row tile
  const int lane = tid & 63;
  const int l15 = lane & 15, l4 = lane >> 4, l7 = lane & 7;
  const bool hiHalf = (lane & 8) != 0;
  const bool oddLane = (lane & 1) != 0;

  // ---- weight fragments in registers for all 512 steps ----
  bf16x8 bx0[16], bx1[16], bh0[16], bh1[16];
  {
    const int cg0 = wg * 2, cg1 = wg * 2 + 1;
    #pragma unroll
    for (int ks = 0; ks < 16; ++ks) {
      bx0[ks] = __builtin_bit_cast(bf16x8, Wxp[(cg0 * 16 + ks) * 64 + lane]);
      bx1[ks] = __builtin_bit_cast(bf16x8, Wxp[(cg1 * 16 + ks) * 64 + lane]);
      bh0[ks] = __builtin_bit_cast(bf16x8, Whp[(cg0 * 16 + ks) * 64 + lane]);
      bh1[ks] = __builtin_bit_cast(bf16x8, Whp[(cg1 * 16 + ks) * 64 + lane]);
    }
  }
  const float bias0 = bcat[wg * 32 + l15];
  const float bias1 = bcat[wg * 32 + 16 + l15];

  const int arow = w * 16 + l15;       // A-operand row (batch index b)
  const int hcol = wg * 8 + l7;        // owned h column
  float c_state[2] = {0.f, 0.f};

  f32x4 acc0, acc1;

  auto xpart = [&](int tt) {
    acc0 = f32x4{bias0, bias0, bias0, bias0};
    acc1 = f32x4{bias1, bias1, bias1, bias1};
    const float* xs = x + ((size_t)tt * NB + arow) * ND + l4 * 8;
    #pragma unroll
    for (int ks = 0; ks < 16; ++ks) {
      float4 f0 = *(const float4*)(xs + ks * 32);
      float4 f1 = *(const float4*)(xs + ks * 32 + 4);
      unsigned int u0 = __builtin_amdgcn_perm(__builtin_bit_cast(unsigned int, f0.y),
                                              __builtin_bit_cast(unsigned int, f0.x), 0x07060302u);
      unsigned int u1 = __builtin_amdgcn_perm(__builtin_bit_cast(unsigned int, f0.w),
                                              __builtin_bit_cast(unsigned int, f0.z), 0x07060302u);
      unsigned int u2 = __builtin_amdgcn_perm(__builtin_bit_cast(unsigned int, f1.y),
                                              __builtin_bit_cast(unsigned int, f1.x), 0x07060302u);
      unsigned int u3 = __builtin_amdgcn_perm(__builtin_bit_cast(unsigned int, f1.w),
                                              __builtin_bit_cast(unsigned int, f1.z), 0x07060302u);
      uint4 uu; uu.x = u0; uu.y = u1; uu.z = u2; uu.w = u3;
      bf16x8 a = __builtin_bit_cast(bf16x8, uu);
      acc0 = __builtin_amdgcn_mfma_f32_16x16x32_bf16(a, bx0[ks], acc0, 0, 0, 0);
      acc1 = __builtin_amdgcn_mfma_f32_16x16x32_bf16(a, bx1[ks], acc1, 0, 0, 0);
    }
  };

  xpart(0);

  #pragma unroll 1
  for (int t = 0; t < NT; ++t) {
    if (t > 0) {
      // ---- wait: all WGs published step t-1 (flag >= t; allow skew of 1) ----
      if (tid < NWG) {
        unsigned want = (unsigned)t;
        while (true) {
          unsigned f = __hip_atomic_load(&flags[tid], __ATOMIC_RELAXED,
                                         __HIP_MEMORY_SCOPE_AGENT);
          if ((unsigned)(f - want) <= 1u) break;
        }
      }
      __syncthreads();

      // ---- h-part: acc += H_{t-1} @ Wh ; H read via sc0 sc1 (bypass stale L2) ----
      const unsigned short* hsrc = hb + ((t + 1) & 1) * (NB * NH) + arow * NH + l4 * 8;
      uint4 ahw[16];
      #pragma unroll
      for (int ks = 0; ks < 16; ++ks) {
        asm volatile("global_load_dwordx4 %0, %1, off sc0 sc1"
                     : "=v"(ahw[ks]) : "v"(hsrc + ks * 32) : "memory");
      }
      asm volatile("s_waitcnt vmcnt(0)" ::: "memory");
      __builtin_amdgcn_sched_barrier(0);
      #pragma unroll
      for (int ks = 0; ks < 16; ++ks) {
        bf16x8 a = __builtin_bit_cast(bf16x8, ahw[ks]);
        acc0 = __builtin_amdgcn_mfma_f32_16x16x32_bf16(a, bh0[ks], acc0, 0, 0, 0);
        acc1 = __builtin_amdgcn_mfma_f32_16x16x32_bf16(a, bh1[ks], acc1, 0, 0, 0);
      }
    }

    // ---- gate epilogue: each lane handles 2 of the 4 acc rows (j split by lane&8) ----
    float hv[2];
    int brow[2];
    #pragma unroll
    for (int jj = 0; jj < 2; ++jj) {
      float a0own = hiHalf ? acc0[2 + jj] : acc0[jj];
      float a0opp = hiHalf ? acc0[jj]     : acc0[2 + jj];
      float a1own = hiHalf ? acc1[2 + jj] : acc1[jj];
      float a1opp = hiHalf ? acc1[jj]     : acc1[2 + jj];
      float a0x = __shfl_xor(a0opp, 8);
      float a1x = __shfl_xor(a1opp, 8);
      float pi = hiHalf ? a0x   : a0own;   // gate i  (packed cols 0..7)
      float pf = hiHalf ? a0own : a0x;     // gate f  (cols 8..15)
      float po = hiHalf ? a1x   : a1own;   // gate o  (cols 16..23)
      float pc = hiHalf ? a1own : a1x;     // gate c~ (cols 24..31)
      float I = sigm(pi), F = sigm(pf), O = sigm(po), Cc = tanhfast(pc);
      float c = F * c_state[jj] + I * Cc;
      c_state[jj] = c;
      hv[jj] = O * tanhfast(c);
      int j = (hiHalf ? 2 : 0) + jj;
      brow[jj] = w * 16 + l4 * 4 + j;
    }

    // ---- publish H_t: pack 2 adjacent cols into one dword, relaxed sc1 store ----
    {
      float e0 = __shfl_xor(hv[0], 1);   // partner's hv[0]
      float e1 = __shfl_xor(hv[1], 1);   // partner's hv[1]
      unsigned int val = oddLane
          ? ((unsigned)f2bf(e1) | ((unsigned)f2bf(hv[1]) << 16))
          : ((unsigned)f2bf(hv[0]) | ((unsigned)f2bf(e0) << 16));
      int row = oddLane ? brow[1] : brow[0];
      int col = oddLane ? (hcol - 1) : hcol;
      unsigned int* dst = (unsigned int*)(hb + (t & 1) * (NB * NH) + row * NH + col);
      __hip_atomic_store(dst, val, __ATOMIC_RELAXED, __HIP_MEMORY_SCOPE_AGENT);
    }

    __syncthreads();   // pre-barrier s_waitcnt vmcnt(0) => all H stores at IF$
    if (tid == 0)
      __hip_atomic_store(&flags[wg], (unsigned)(t + 1), __ATOMIC_RELAXED,
                         __HIP_MEMORY_SCOPE_AGENT);

    // ---- off critical path: fp32 outputs + next step's x projection ----
    #pragma unroll
    for (int jj = 0; jj < 2; ++jj)
      __builtin_nontemporal_store(hv[jj], &out[((size_t)t * NB + brow[jj]) * NH + hcol]);
    if (t == NT - 1) {
      #pragma unroll
      for (int jj = 0; jj < 2; ++jj) {
        out[(size_t)NT * NB * NH + brow[jj] * NH + hcol] = hv[jj];                 // Hf
        out[(size_t)NT * NB * NH + NB * NH + brow[jj] * NH + hcol] = c_state[jj];  // Cf
      }
    } else {
      xpart(t + 1);
    }
  }
}

extern "C" void kernel_launch(void* const* d_in, const int* in_sizes, int n_in,
                              void* d_out, int out_size, void* d_ws, size_t ws_size,
                              hipStream_t stream) {
  const float* x = (const float*)d_in[0];
  const float* Wx0 = (const float*)d_in[1];
  const float* Wh0 = (const float*)d_in[2];
  const float* b0  = (const float*)d_in[3];
  const float* Wx1 = (const float*)d_in[4];
  const float* Wh1 = (const float*)d_in[5];
  const float* b1  = (const float*)d_in[6];
  const float* Wx2 = (const float*)d_in[7];
  const float* Wh2 = (const float*)d_in[8];
  const float* b2  = (const float*)d_in[9];
  const float* Wx3 = (const float*)d_in[10];
  const float* Wh3 = (const float*)d_in[11];
  const float* b3  = (const float*)d_in[12];

  char* ws = (char*)d_ws;
  if (ws_size < (size_t)WS_NEED) return;
  uint4* Wxp = (uint4*)(ws + WXP_OFF);
  uint4* Whp = (uint4*)(ws + WHP_OFF);
  float* bcat = (float*)(ws + BCAT_OFF);
  unsigned short* hbuf = (unsigned short*)(ws + HBUF_OFF);
  unsigned int* flags = (unsigned int*)(ws + FLAG_OFF);

  // zero epoch flags (H buffer needs no init: t=0 skips the H-part, H_0 == 0)
  hipMemsetAsync(ws + FLAG_OFF, 0, 256u, stream);

  pack_weights<<<1024, 256, 0, stream>>>(Wx0, Wh0, b0, Wx1, Wh1, b1,
                                         Wx2, Wh2, b2, Wx3, Wh3, b3,
                                         Wxp, Whp, bcat);

  lstm_scan<<<NWG, 256, 0, stream>>>(x, Wxp, Whp, bcat, hbuf, flags, (float*)d_out);
}